// Round 2
// baseline (458.267 us; speedup 1.0000x reference)
//
#include <hip/hip_runtime.h>
#include <hip/hip_bf16.h>
#include <stdint.h>

// Problem constants (B,H,S,D) = (2,16,2048,64); softmax is over the HEAD axis.
#define B_ 2
#define H_ 16
#define S_ 2048
#define D_ 64

typedef __attribute__((ext_vector_type(8))) short bf16x8;
typedef __attribute__((ext_vector_type(4))) float f32x4;

__device__ __forceinline__ short f2bf(float x){
  union { float f; uint32_t u; } v; v.f = x;
  uint32_t r = v.u + 0x7FFFu + ((v.u >> 16) & 1u);   // round-to-nearest-even
  return (short)(r >> 16);
}
__device__ __forceinline__ float bf2f(short s){
  union { uint32_t u; float f; } v; v.u = ((uint32_t)(uint16_t)s) << 16;
  return v.f;
}

// ---------- prep 1: K -> bf16 hi/lo split ----------
__global__ __launch_bounds__(256) void cast_k(const float* __restrict__ K,
                                              short* __restrict__ Khi,
                                              short* __restrict__ Klo){
  size_t idx = ((size_t)blockIdx.x * 256 + threadIdx.x) * 8;
  float4 a = *(const float4*)(K + idx);
  float4 b = *(const float4*)(K + idx + 4);
  float v[8] = {a.x,a.y,a.z,a.w,b.x,b.y,b.z,b.w};
  bf16x8 vh, vl;
  #pragma unroll
  for (int i = 0; i < 8; ++i){
    short hi = f2bf(v[i]);
    vh[i] = hi;
    vl[i] = f2bf(v[i] - bf2f(hi));
  }
  *(bf16x8*)(Khi + idx) = vh;
  *(bf16x8*)(Klo + idx) = vl;
}

// ---------- prep 2: V -> Vt[b,h,d,k] bf16 (transposed) ----------
__global__ __launch_bounds__(256) void transpose_v(const float* __restrict__ V,
                                                   short* __restrict__ Vt){
  __shared__ float T[64][65];
  int bh = blockIdx.x >> 5;          // 0..31  (B*H)
  int k0 = (blockIdx.x & 31) * 64;   // S/64 = 32 chunks
  int t = threadIdx.x;
  {
    int col = (t & 15) * 4;          // d
    #pragma unroll
    for (int i = 0; i < 4; ++i){
      int row = (t >> 4) + i * 16;   // k within chunk
      float4 a = *(const float4*)(V + ((size_t)bh * S_ + k0 + row) * D_ + col);
      T[col+0][row] = a.x; T[col+1][row] = a.y; T[col+2][row] = a.z; T[col+3][row] = a.w;
    }
  }
  __syncthreads();
  {
    int d  = t >> 2;
    int kk = (t & 3) * 16;
    bf16x8 o0, o1;
    #pragma unroll
    for (int j = 0; j < 8; ++j){
      o0[j] = f2bf(T[d][kk + j]);
      o1[j] = f2bf(T[d][kk + 8 + j]);
    }
    short* dst = Vt + ((size_t)bh * D_ + d) * S_ + k0 + kk;
    *(bf16x8*)(dst)     = o0;
    *(bf16x8*)(dst + 8) = o1;
  }
}

// ---------- main fused kernel ----------
// grid = B * S/16 = 256 blocks, 1024 threads (16 waves), wave w <-> head w.
// Per 32-wide k-tile:
//   phase A: scores via MFMA (hi*hi + hi*lo + lo*hi), e = exp(s*scale) -> LDS (swizzled)
//   phase B: 512 threads reduce over 16 head planes -> z = mask?1/sum:0, c = mask?0:1/16
//   phase C: p = e*z + c ; nontemporal store p_attn ; PV MFMA with Vt fragments
__global__ __launch_bounds__(1024, 4) void attn_main(
    const float* __restrict__ Q, const short* __restrict__ Khi,
    const short* __restrict__ Klo, const short* __restrict__ Vt,
    const int* __restrict__ mask, float* __restrict__ out,
    float* __restrict__ pout)
{
  __shared__ float sc[2][H_][512];   // 64 KB  (double-buffered e-values, swizzled k)
  __shared__ float zb[2][512];       // 4 KB
  __shared__ float cb[2][512];       // 4 KB

  const int tid  = threadIdx.x;
  const int h    = tid >> 6;         // wave id == head
  const int lane = tid & 63;
  const int g    = lane >> 4;        // 0..3
  const int lr   = lane & 15;

  const int b  = blockIdx.x >> 7;          // 128 blocks per b
  const int q0 = (blockIdx.x & 127) << 4;  // 16 q-rows per block

  const size_t bh = (size_t)b * H_ + h;

  // Q fragments (A-operand): lane holds Q[q0+lr][c*32 + g*8 + i], hi/lo split
  bf16x8 qhi[2], qlo[2];
  {
    const float* qp = Q + (bh * S_ + q0 + lr) * D_ + g * 8;
    #pragma unroll
    for (int c = 0; c < 2; ++c){
      float4 a  = *(const float4*)(qp + c*32);
      float4 d4 = *(const float4*)(qp + c*32 + 4);
      float v[8] = {a.x,a.y,a.z,a.w,d4.x,d4.y,d4.z,d4.w};
      #pragma unroll
      for (int i = 0; i < 8; ++i){
        short hi = f2bf(v[i]);
        qhi[c][i] = hi;
        qlo[c][i] = f2bf(v[i] - bf2f(hi));
      }
    }
  }

  f32x4 o[4];
  #pragma unroll
  for (int j = 0; j < 4; ++j) o[j] = (f32x4){0.f,0.f,0.f,0.f};

  const int swzq = 4 * (lr & 7);     // stage-C swizzle for q = lr

  const short* kbase_hi = Khi + (bh * S_ + lr) * D_ + g * 8;
  const short* kbase_lo = Klo + (bh * S_ + lr) * D_ + g * 8;
  const short* vbase    = Vt  + (bh * D_ + lr) * S_ + g * 8;
  float*       pbase    = pout + (bh * S_ + q0 + lr) * S_ + g * 8;

  for (int it = 0; it < S_/32; ++it){
    const int k0  = it * 32;
    const int buf = it & 1;

    // ---- phase A: scores + exp -> LDS ----
    f32x4 s[2];
    #pragma unroll
    for (int t = 0; t < 2; ++t){
      s[t] = (f32x4){0.f,0.f,0.f,0.f};
      #pragma unroll
      for (int c = 0; c < 2; ++c){
        bf16x8 kh = *(const bf16x8*)(kbase_hi + (size_t)(k0 + 16*t) * D_ + c*32);
        bf16x8 kl = *(const bf16x8*)(kbase_lo + (size_t)(k0 + 16*t) * D_ + c*32);
        s[t] = __builtin_amdgcn_mfma_f32_16x16x32_bf16(qhi[c], kh, s[t], 0, 0, 0);
        s[t] = __builtin_amdgcn_mfma_f32_16x16x32_bf16(qlo[c], kh, s[t], 0, 0, 0);
        s[t] = __builtin_amdgcn_mfma_f32_16x16x32_bf16(qhi[c], kl, s[t], 0, 0, 0);
      }
    }
    #pragma unroll
    for (int t = 0; t < 2; ++t){
      #pragma unroll
      for (int r = 0; r < 4; ++r){
        int q = 4*g + r;             // C/D layout: row = 4*(lane>>4)+reg
        int k = 16*t + lr;           // col = lane&15 (+16 for tile t=1)
        float e = __expf(s[t][r] * 0.125f);
        sc[buf][h][q*32 + (k ^ (4*(q&7)))] = e;
      }
    }
    __syncthreads();

    // ---- phase B: denom over heads, z/c coefficients ----
    if (tid < 512){
      int q = tid >> 5, k = tid & 31;
      int ks = q*32 + (k ^ (4*(q&7)));
      float dsum = 0.f;
      #pragma unroll
      for (int hh = 0; hh < H_; ++hh) dsum += sc[buf][hh][ks];
      int m = __builtin_nontemporal_load(mask + ((size_t)b * S_ + q0 + q) * S_ + k0 + k);
      zb[buf][ks] = m ? (1.0f / dsum) : 0.0f;
      cb[buf][ks] = m ? 0.0f : 0.0625f;
    }
    __syncthreads();

    // ---- phase C: p = e*z + c ; write p_attn ; PV MFMA ----
    {
      int b1 = (8*g) ^ swzq;         // k = 8g..8g+3 quad
      int b2 = b1 ^ 4;               // k = 8g+4..8g+7 quad
      const float* sp = &sc[buf][h][lr*32];
      const float* zp = &zb[buf][lr*32];
      const float* cp = &cb[buf][lr*32];
      float4 e0 = *(const float4*)(sp + b1);
      float4 e1 = *(const float4*)(sp + b2);
      float4 z0 = *(const float4*)(zp + b1);
      float4 z1 = *(const float4*)(zp + b2);
      float4 c0 = *(const float4*)(cp + b1);
      float4 c1 = *(const float4*)(cp + b2);
      float p[8];
      p[0] = e0.x*z0.x + c0.x;  p[1] = e0.y*z0.y + c0.y;
      p[2] = e0.z*z0.z + c0.z;  p[3] = e0.w*z0.w + c0.w;
      p[4] = e1.x*z1.x + c1.x;  p[5] = e1.y*z1.y + c1.y;
      p[6] = e1.z*z1.z + c1.z;  p[7] = e1.w*z1.w + c1.w;

      f32x4 p0 = {p[0],p[1],p[2],p[3]};
      f32x4 p1 = {p[4],p[5],p[6],p[7]};
      __builtin_nontemporal_store(p0, (f32x4*)(pbase + k0));
      __builtin_nontemporal_store(p1, (f32x4*)(pbase + k0 + 4));

      bf16x8 pa;
      #pragma unroll
      for (int i = 0; i < 8; ++i) pa[i] = f2bf(p[i]);

      #pragma unroll
      for (int j = 0; j < 4; ++j){
        bf16x8 vb = *(const bf16x8*)(vbase + (size_t)(16*j) * S_ + k0);
        o[j] = __builtin_amdgcn_mfma_f32_16x16x32_bf16(pa, vb, o[j], 0, 0, 0);
      }
    }
    // next iteration writes buf^1; barrier pair above orders reuse of buf
  }

  // ---- epilogue: out[b,h,q0+4g+r][16j+lr] ----
  #pragma unroll
  for (int j = 0; j < 4; ++j){
    #pragma unroll
    for (int r = 0; r < 4; ++r){
      out[(bh * S_ + q0 + 4*g + r) * D_ + 16*j + lr] = o[j][r];
    }
  }
}

extern "C" void kernel_launch(void* const* d_in, const int* in_sizes, int n_in,
                              void* d_out, int out_size, void* d_ws, size_t ws_size,
                              hipStream_t stream){
  const float* Q    = (const float*)d_in[0];
  const float* K    = (const float*)d_in[1];
  const float* V    = (const float*)d_in[2];
  const int*   mask = (const int*)d_in[3];

  const size_t nkv = (size_t)B_ * H_ * S_ * D_;   // 4,194,304

  short* Khi = (short*)d_ws;          // 8.4 MB
  short* Klo = Khi + nkv;             // 8.4 MB
  short* Vt  = Klo + nkv;             // 8.4 MB  (total 25.2 MB of ws)

  float* out  = (float*)d_out;        // [B,H,S,D]
  float* pout = out + nkv;            // [B,H,S,S]

  cast_k<<<(int)(nkv / (256 * 8)), 256, 0, stream>>>(K, Khi, Klo);
  transpose_v<<<B_ * H_ * (S_ / 64), 256, 0, stream>>>(V, Vt);
  attn_main<<<B_ * (S_ / 16), 1024, 0, stream>>>(Q, Khi, Klo, Vt, mask, out, pout);
}